// Round 5
// baseline (345.182 us; speedup 1.0000x reference)
//
#include <hip/hip_runtime.h>
#include <cstdint>

// ---------------------------------------------------------------------------
// DefaultAttention: x[4,2048,1024] fp32; k=xWk^T+bk, q=xWq^T+bq, v=xWv^T+bv;
// sim = k q^T / 32 (causal tril), attn = softmax(sim), out = attn @ v (fp32).
// R5: A-operand loaded global->registers (MFMA A-frag = 16B contiguous row
// chunk) with 1-iter reg prefetch; only B goes through the dbuf LDS path.
// Cuts per-iter LDS traffic 48KB->24KB (the R4 wall) and decouples A from
// the barrier. B keeps XOR-swizzled conflict-free staging.
// ---------------------------------------------------------------------------

typedef __attribute__((ext_vector_type(8))) _Float16 f16x8;
typedef __attribute__((ext_vector_type(4))) float f32x4;

__device__ __forceinline__ unsigned short f2h(float x) {
  return __builtin_bit_cast(unsigned short, (_Float16)x);
}

// async global->LDS, 16B per lane; LDS dest = wave-uniform base + lane*16
__device__ __forceinline__ void lds_dma16(const void* g, void* l) {
  auto gp = reinterpret_cast<const __attribute__((address_space(1))) void*>(
      reinterpret_cast<uintptr_t>(g));
  auto lp = reinterpret_cast<__attribute__((address_space(3))) void*>(
      reinterpret_cast<uintptr_t>(l));
  __builtin_amdgcn_global_load_lds(gp, lp, 16, 0, 0);
}

// ---------------------------------------------------------------------------
// Core: C[128x128] += A[128xK] * B[128xK]^T  (row-major, K contiguous).
// A: global->VGPR fragments (lane rr = row wm*64+i*16+rr, cols qq*8..+7),
//    prefetched one K-iter ahead (a_nxt).
// B: BK=32 XOR-swizzled LDS, double-buffered, single-barrier pipeline.
// ---------------------------------------------------------------------------
__device__ __forceinline__ void gemm128_rA(
    const unsigned short* __restrict__ Ag, const unsigned short* __restrict__ Bg,
    int lda, int ldb, int nk, unsigned short* Bs, f32x4 acc[4][4]) {
  const int tid = threadIdx.x;
  const int lane = tid & 63, wave = tid >> 6;
  const int wm = wave >> 1, wn = wave & 1;
  const int sr = lane >> 2;                               // staging row in chunk
  const int scb = (((lane & 3) ^ ((lane >> 3) & 3)) * 8); // swizzled src col
  const int rr = lane & 15, qq = lane >> 4;
  const int slot = ((qq ^ ((rr >> 1) & 3)) * 8);          // swizzled read col

#pragma unroll
  for (int i = 0; i < 4; ++i)
#pragma unroll
    for (int j = 0; j < 4; ++j) {
      f32x4 z = {0.f, 0.f, 0.f, 0.f};
      acc[i][j] = z;
    }

  // A fragment base: row (wm*64 + i*16 + rr), col qq*8 (16B aligned)
  const unsigned short* Arow = Ag + (size_t)(wm * 64 + rr) * lda + qq * 8;
  const size_t astep = (size_t)16 * lda;

  f16x8 a_cur[4], a_nxt[4];
#pragma unroll
  for (int i = 0; i < 4; ++i)
    a_cur[i] = *(const f16x8*)(Arow + (size_t)i * astep);

  // prologue: stage B k0=0 into buf 0 (8 chunks of 16 rows; wave w: 2w,2w+1)
#pragma unroll
  for (int c = 0; c < 2; ++c) {
    int chunk = wave * 2 + c;
    int row = chunk * 16 + sr;
    lds_dma16(Bg + (size_t)row * ldb + scb, Bs + chunk * 512);
  }

  int buf = 0;
  for (int k0 = 0; k0 < nk; k0 += 32) {
    __syncthreads();  // drains B staging issued one compute-phase ago
    const int kn = k0 + 32;
    if (kn < nk) {
      // prefetch next A frags into regs (waited on only next iter)
#pragma unroll
      for (int i = 0; i < 4; ++i)
        a_nxt[i] = *(const f16x8*)(Arow + (size_t)i * astep + kn);
      unsigned short* Bn = Bs + (buf ^ 1) * 4096;
#pragma unroll
      for (int c = 0; c < 2; ++c) {
        int chunk = wave * 2 + c;
        int row = chunk * 16 + sr;
        lds_dma16(Bg + (size_t)row * ldb + kn + scb, Bn + chunk * 512);
      }
    }

    f16x8 bf[4];
    const unsigned short* Br = Bs + buf * 4096 + (wn * 64 + rr) * 32 + slot;
#pragma unroll
    for (int j = 0; j < 4; ++j) bf[j] = *(const f16x8*)(Br + j * 512);
#pragma unroll
    for (int i = 0; i < 4; ++i)
#pragma unroll
      for (int j = 0; j < 4; ++j)
        acc[i][j] = __builtin_amdgcn_mfma_f32_16x16x32_f16(a_cur[i], bf[j],
                                                           acc[i][j], 0, 0, 0);
#pragma unroll
    for (int i = 0; i < 4; ++i) a_cur[i] = a_nxt[i];
    buf ^= 1;
  }
}

// ---------------------------------------------------------------------------
// fp32 -> f16 convert: x (2097152 float4) then Wk,Wq,Wv (262144 float4 each)
// into contiguous [xh | wh]; last 8 blocks zero rsum (8192 floats).
// ---------------------------------------------------------------------------
__global__ void cvt_kernel(const float* __restrict__ x,
                           const float* __restrict__ w0,
                           const float* __restrict__ w1,
                           const float* __restrict__ w2,
                           unsigned short* __restrict__ dst,
                           float* __restrict__ rsum) {
  int i = blockIdx.x * 256 + threadIdx.x;
  if (i >= 2883584) {  // rsum zero blocks
    int z2 = i - 2883584;
    float4 z = {0.f, 0.f, 0.f, 0.f};
    ((float4*)rsum)[z2] = z;
    return;
  }
  const float* s;
  size_t si;
  if (i < 2097152) {
    s = x; si = i;
  } else {
    int j = i - 2097152;
    int z = j >> 18;
    s = (z == 0) ? w0 : ((z == 1) ? w1 : w2);
    si = j & 262143;
  }
  float4 f = ((const float4*)s)[si];
  ushort4 u;
  u.x = f2h(f.x); u.y = f2h(f.y); u.z = f2h(f.z); u.w = f2h(f.w);
  ((ushort4*)dst)[i] = u;
}

// ---------------------------------------------------------------------------
// QKV projection: dst[m,f] = sum_e xh[m,e]*W[f,e] + bias[f]   (f16 out)
// grid (24, 64): x = z*8 + tn (z fast -> xh slab reused across all 24).
// ---------------------------------------------------------------------------
__global__ __launch_bounds__(256) void qkv_gemm_kernel(
    const unsigned short* __restrict__ xh, const unsigned short* __restrict__ wh,
    const float* __restrict__ bk, const float* __restrict__ bq,
    const float* __restrict__ bv, unsigned short* __restrict__ kh,
    unsigned short* __restrict__ qh, unsigned short* __restrict__ vh) {
  __shared__ unsigned short Bs[2 * 128 * 32];
  const int tn = blockIdx.x & 7, z = blockIdx.x >> 3;
  const unsigned short* W = wh + (size_t)z * 1048576;
  const float* bias = (z == 0) ? bk : ((z == 1) ? bq : bv);
  unsigned short* dst = (z == 0) ? kh : ((z == 1) ? qh : vh);
  const int tm = blockIdx.y;

  f32x4 acc[4][4];
  gemm128_rA(xh + (size_t)tm * 128 * 1024, W + (size_t)tn * 128 * 1024,
             1024, 1024, 1024, Bs, acc);

  const int lane = threadIdx.x & 63, wave = threadIdx.x >> 6;
  const int wm = wave >> 1, wn = wave & 1, rr = lane & 15, qq = lane >> 4;
  float bj[4];
#pragma unroll
  for (int j = 0; j < 4; ++j)
    bj[j] = bias[tn * 128 + wn * 64 + j * 16 + rr];
#pragma unroll
  for (int i = 0; i < 4; ++i)
#pragma unroll
    for (int reg = 0; reg < 4; ++reg) {
      int gm = tm * 128 + wm * 64 + i * 16 + qq * 4 + reg;
#pragma unroll
      for (int j = 0; j < 4; ++j) {
        int gc = tn * 128 + wn * 64 + j * 16 + rr;
        dst[(size_t)gm * 1024 + gc] = f2h(acc[i][j][reg] + bj[j]);
      }
    }
}

// ---------------------------------------------------------------------------
// v[b,t,d] -> vT[b,d,t]  (f16), 64x64 tiles, ushort4 vectorized
// ---------------------------------------------------------------------------
__global__ __launch_bounds__(256) void transpose_v_kernel(
    const unsigned short* __restrict__ v, unsigned short* __restrict__ vT) {
  __shared__ unsigned short tile[64][65];
  const int b = blockIdx.z;
  const unsigned short* vp = v + (size_t)b * 2048 * 1024;
  unsigned short* vtp = vT + (size_t)b * 1024 * 2048;
  const int t0 = blockIdx.x * 64, d0 = blockIdx.y * 64;
  const int lr = threadIdx.x >> 4, lc = (threadIdx.x & 15) * 4;
#pragma unroll
  for (int p = 0; p < 4; ++p) {
    int tr = p * 16 + lr;
    ushort4 u = *(const ushort4*)(vp + (size_t)(t0 + tr) * 1024 + d0 + lc);
    tile[tr][lc] = u.x; tile[tr][lc + 1] = u.y;
    tile[tr][lc + 2] = u.z; tile[tr][lc + 3] = u.w;
  }
  __syncthreads();
#pragma unroll
  for (int p = 0; p < 4; ++p) {
    int dr = p * 16 + lr;
    ushort4 u;
    u.x = tile[lc][dr]; u.y = tile[lc + 1][dr];
    u.z = tile[lc + 2][dr]; u.w = tile[lc + 3][dr];
    *(ushort4*)(vtp + (size_t)(d0 + dr) * 2048 + t0 + lc) = u;
  }
}

// ---------------------------------------------------------------------------
// scores: P[b,s,t] = exp(k[s].q[t]/32 - 4) for t<=s else 0  (f16), plus
// fused row-sum atomics. 1-D triangular grid (136 tiles), y = batch.
// ---------------------------------------------------------------------------
__global__ __launch_bounds__(256) void scores_kernel(
    const unsigned short* __restrict__ kh, const unsigned short* __restrict__ qh,
    unsigned short* __restrict__ P, float* __restrict__ rsum) {
  const int b = blockIdx.y;
  int idx = blockIdx.x;
  int ts = (int)((sqrtf(8.0f * idx + 1.0f) - 1.0f) * 0.5f);
  while ((ts + 1) * (ts + 2) / 2 <= idx) ++ts;
  while (ts * (ts + 1) / 2 > idx) --ts;
  const int tt = idx - ts * (ts + 1) / 2;
  __shared__ unsigned short Bs[2 * 128 * 32];

  f32x4 acc[4][4];
  gemm128_rA(kh + ((size_t)(b * 2048 + ts * 128)) * 1024,
             qh + ((size_t)(b * 2048 + tt * 128)) * 1024,
             1024, 1024, 1024, Bs, acc);

  const int lane = threadIdx.x & 63, wave = threadIdx.x >> 6;
  const int wm = wave >> 1, wn = wave & 1, rr = lane & 15, qq = lane >> 4;
  unsigned short* Pb = P + (size_t)b * 2048 * 2048;
  float* rs = rsum + b * 2048;
#pragma unroll
  for (int i = 0; i < 4; ++i)
#pragma unroll
    for (int reg = 0; reg < 4; ++reg) {
      int srow = ts * 128 + wm * 64 + i * 16 + qq * 4 + reg;
      float p = 0.f;
#pragma unroll
      for (int j = 0; j < 4; ++j) {
        int tcol = tt * 128 + wn * 64 + j * 16 + rr;
        float e = (tcol <= srow) ? __expf(acc[i][j][reg] * 0.03125f - 4.0f)
                                 : 0.0f;
        Pb[(size_t)srow * 2048 + tcol] = f2h(e);
        p += e;
      }
#pragma unroll
      for (int off = 1; off < 16; off <<= 1) p += __shfl_xor(p, off);
      if (rr == 0) atomicAdd(rs + srow, p);
    }
}

// ---------------------------------------------------------------------------
// out[b,s,d] = (1/rsum[b,s]) * sum_t P[b,s,t] * vT[b,d,t]   (fp32 out)
// grid (8,16,4); K truncated to (ts+1)*128; y reversed (big-K first).
// ---------------------------------------------------------------------------
__global__ __launch_bounds__(256) void pv_gemm_kernel(
    const unsigned short* __restrict__ P, const unsigned short* __restrict__ vT,
    const float* __restrict__ rsum, float* __restrict__ out) {
  const int td = blockIdx.x, ts = 15 - blockIdx.y, b = blockIdx.z;
  __shared__ unsigned short Bs[2 * 128 * 32];

  f32x4 acc[4][4];
  gemm128_rA(P + ((size_t)(b * 2048 + ts * 128)) * 2048,
             vT + ((size_t)(b * 1024 + td * 128)) * 2048,
             2048, 2048, (ts + 1) * 128, Bs, acc);

  const int lane = threadIdx.x & 63, wave = threadIdx.x >> 6;
  const int wm = wave >> 1, wn = wave & 1, rr = lane & 15, qq = lane >> 4;
#pragma unroll
  for (int i = 0; i < 4; ++i)
#pragma unroll
    for (int reg = 0; reg < 4; ++reg) {
      int srow = ts * 128 + wm * 64 + i * 16 + qq * 4 + reg;
      float rv = __builtin_amdgcn_rcpf(rsum[b * 2048 + srow]);
#pragma unroll
      for (int j = 0; j < 4; ++j) {
        int dcol = td * 128 + wn * 64 + j * 16 + rr;
        out[((size_t)(b * 2048 + srow)) * 1024 + dcol] = acc[i][j][reg] * rv;
      }
    }
}

// ---------------------------------------------------------------------------
// launch
// ---------------------------------------------------------------------------
extern "C" void kernel_launch(void* const* d_in, const int* in_sizes, int n_in,
                              void* d_out, int out_size, void* d_ws,
                              size_t ws_size, hipStream_t stream) {
  const float* x  = (const float*)d_in[0];
  const float* Wk = (const float*)d_in[1];
  const float* bk = (const float*)d_in[2];
  const float* Wq = (const float*)d_in[3];
  const float* bq = (const float*)d_in[4];
  const float* Wv = (const float*)d_in[5];
  const float* bv = (const float*)d_in[6];
  float* out = (float*)d_out;

  char* ws = (char*)d_ws;
  const size_t MB = 1ull << 20;
  // Aliased layout (86 MB + 32 KB): P overlays xh/wh/vh (dead by scores).
  unsigned short* xh = (unsigned short*)(ws + 0);        // 16 MB  [0,16)
  unsigned short* wh = (unsigned short*)(ws + 16 * MB);  //  6 MB  [16,22)
  unsigned short* vh = (unsigned short*)(ws + 22 * MB);  // 16 MB  [22,38)
  unsigned short* P  = (unsigned short*)(ws + 0);        // 32 MB  [0,32) alias
  unsigned short* kh = (unsigned short*)(ws + 38 * MB);  // 16 MB  [38,54)
  unsigned short* qh = (unsigned short*)(ws + 54 * MB);  // 16 MB  [54,70)
  unsigned short* vT = (unsigned short*)(ws + 70 * MB);  // 16 MB  [70,86)
  float* rsum = (float*)(ws + 86 * MB);                  // 32 KB

  // 1) converts (x + 3 W) + rsum zero-init (last 8 blocks)
  cvt_kernel<<<11272, 256, 0, stream>>>(x, Wk, Wq, Wv, xh, rsum);
  // 2) QKV projections (f16)
  qkv_gemm_kernel<<<dim3(24, 64), 256, 0, stream>>>(xh, wh, bk, bq, bv,
                                                    kh, qh, vh);
  // 3) v -> vT (vectorized)
  transpose_v_kernel<<<dim3(32, 16, 4), 256, 0, stream>>>(vh, vT);
  // 4) masked exp(scores) + fused row-sum atomics (triangular grid)
  scores_kernel<<<dim3(136, 4), 256, 0, stream>>>(kh, qh, P, rsum);
  // 5) (P @ v) * (1/rsum) -> out
  pv_gemm_kernel<<<dim3(8, 16, 4), 256, 0, stream>>>(P, vT, rsum, out);
}

// Round 6
// 283.235 us; speedup vs baseline: 1.2187x; 1.2187x over previous
//
#include <hip/hip_runtime.h>
#include <cstdint>

// ---------------------------------------------------------------------------
// DefaultAttention: x[4,2048,1024] fp32; k=xWk^T+bk, q=xWq^T+bq, v=xWv^T+bv;
// sim = k q^T / 32 (causal tril), attn = softmax(sim), out = attn @ v (fp32).
// R6: qkv reverted to R4's verified dbuf gemm128 (A-in-reg regressed: 1-deep
// reg prefetch exposes global latency). scores/pv move to 64x64 tiles ->
// ~8 blocks/CU occupancy (they were latency-starved at ~2 blocks/CU).
// ---------------------------------------------------------------------------

typedef __attribute__((ext_vector_type(8))) _Float16 f16x8;
typedef __attribute__((ext_vector_type(4))) float f32x4;

__device__ __forceinline__ unsigned short f2h(float x) {
  return __builtin_bit_cast(unsigned short, (_Float16)x);
}

// async global->LDS, 16B per lane; LDS dest = wave-uniform base + lane*16
__device__ __forceinline__ void lds_dma16(const void* g, void* l) {
  auto gp = reinterpret_cast<const __attribute__((address_space(1))) void*>(
      reinterpret_cast<uintptr_t>(g));
  auto lp = reinterpret_cast<__attribute__((address_space(3))) void*>(
      reinterpret_cast<uintptr_t>(l));
  __builtin_amdgcn_global_load_lds(gp, lp, 16, 0, 0);
}

// ---------------------------------------------------------------------------
// gemm128: C[128x128] += A[128xK] * B[128xK]^T  (row-major, K contiguous).
// BK=32, XOR-swizzled [row][32] LDS (conflict-free), double-buffered
// single-barrier pipeline (R4-verified).
// ---------------------------------------------------------------------------
__device__ __forceinline__ void gemm128(const unsigned short* __restrict__ Ag,
                                        const unsigned short* __restrict__ Bg,
                                        int lda, int ldb, int nk,
                                        unsigned short* As, unsigned short* Bs,
                                        f32x4 acc[4][4]) {
  const int tid = threadIdx.x;
  const int lane = tid & 63, wave = tid >> 6;
  const int wm = wave >> 1, wn = wave & 1;
  const int sr = lane >> 2;                               // staging row in chunk
  const int scb = (((lane & 3) ^ ((lane >> 3) & 3)) * 8); // swizzled src col
  const int rr = lane & 15, qq = lane >> 4;
  const int slot = ((qq ^ ((rr >> 1) & 3)) * 8);          // swizzled read col

#pragma unroll
  for (int i = 0; i < 4; ++i)
#pragma unroll
    for (int j = 0; j < 4; ++j) {
      f32x4 z = {0.f, 0.f, 0.f, 0.f};
      acc[i][j] = z;
    }

  // prologue: stage k0=0 into buf 0 (8 chunks of 16 rows; wave w: 2w,2w+1)
#pragma unroll
  for (int c = 0; c < 2; ++c) {
    int chunk = wave * 2 + c;
    int row = chunk * 16 + sr;
    lds_dma16(Ag + (size_t)row * lda + scb, As + chunk * 512);
    lds_dma16(Bg + (size_t)row * ldb + scb, Bs + chunk * 512);
  }

  int buf = 0;
  for (int k0 = 0; k0 < nk; k0 += 32) {
    __syncthreads();  // drains staging issued one compute-phase ago
    const int kn = k0 + 32;
    if (kn < nk) {
      unsigned short* An = As + (buf ^ 1) * 4096;
      unsigned short* Bn = Bs + (buf ^ 1) * 4096;
#pragma unroll
      for (int c = 0; c < 2; ++c) {
        int chunk = wave * 2 + c;
        int row = chunk * 16 + sr;
        lds_dma16(Ag + (size_t)row * lda + kn + scb, An + chunk * 512);
        lds_dma16(Bg + (size_t)row * ldb + kn + scb, Bn + chunk * 512);
      }
    }

    f16x8 af[4], bf[4];
    const unsigned short* Ar = As + buf * 4096 + (wm * 64 + rr) * 32 + slot;
    const unsigned short* Br = Bs + buf * 4096 + (wn * 64 + rr) * 32 + slot;
#pragma unroll
    for (int i = 0; i < 4; ++i) af[i] = *(const f16x8*)(Ar + i * 512);
#pragma unroll
    for (int j = 0; j < 4; ++j) bf[j] = *(const f16x8*)(Br + j * 512);
#pragma unroll
    for (int i = 0; i < 4; ++i)
#pragma unroll
      for (int j = 0; j < 4; ++j)
        acc[i][j] = __builtin_amdgcn_mfma_f32_16x16x32_f16(af[i], bf[j],
                                                           acc[i][j], 0, 0, 0);
    buf ^= 1;
  }
}

// ---------------------------------------------------------------------------
// gemm64: C[64x64] += A[64xK] * B[64xK]^T. Same staging/swizzle pattern
// (8 chunks of 16 rows: 4 A + 4 B; wave w stages A-chunk w, B-chunk w).
// Wave w owns 32x32 quadrant (2x2 frags, 16 AGPR) -> high occupancy.
// ---------------------------------------------------------------------------
__device__ __forceinline__ void gemm64(const unsigned short* __restrict__ Ag,
                                       const unsigned short* __restrict__ Bg,
                                       int lda, int ldb, int nk,
                                       unsigned short* As, unsigned short* Bs,
                                       f32x4 acc[2][2]) {
  const int tid = threadIdx.x;
  const int lane = tid & 63, wave = tid >> 6;
  const int wm = wave >> 1, wn = wave & 1;
  const int sr = lane >> 2;
  const int scb = (((lane & 3) ^ ((lane >> 3) & 3)) * 8);
  const int rr = lane & 15, qq = lane >> 4;
  const int slot = ((qq ^ ((rr >> 1) & 3)) * 8);

#pragma unroll
  for (int i = 0; i < 2; ++i)
#pragma unroll
    for (int j = 0; j < 2; ++j) {
      f32x4 z = {0.f, 0.f, 0.f, 0.f};
      acc[i][j] = z;
    }

  {
    int row = wave * 16 + sr;
    lds_dma16(Ag + (size_t)row * lda + scb, As + wave * 512);
    lds_dma16(Bg + (size_t)row * ldb + scb, Bs + wave * 512);
  }

  int buf = 0;
  for (int k0 = 0; k0 < nk; k0 += 32) {
    __syncthreads();
    const int kn = k0 + 32;
    if (kn < nk) {
      int row = wave * 16 + sr;
      lds_dma16(Ag + (size_t)row * lda + kn + scb,
                As + (buf ^ 1) * 2048 + wave * 512);
      lds_dma16(Bg + (size_t)row * ldb + kn + scb,
                Bs + (buf ^ 1) * 2048 + wave * 512);
    }

    f16x8 af[2], bf[2];
    const unsigned short* Ar = As + buf * 2048 + (wm * 32 + rr) * 32 + slot;
    const unsigned short* Br = Bs + buf * 2048 + (wn * 32 + rr) * 32 + slot;
#pragma unroll
    for (int i = 0; i < 2; ++i) af[i] = *(const f16x8*)(Ar + i * 512);
#pragma unroll
    for (int j = 0; j < 2; ++j) bf[j] = *(const f16x8*)(Br + j * 512);
#pragma unroll
    for (int i = 0; i < 2; ++i)
#pragma unroll
      for (int j = 0; j < 2; ++j)
        acc[i][j] = __builtin_amdgcn_mfma_f32_16x16x32_f16(af[i], bf[j],
                                                           acc[i][j], 0, 0, 0);
    buf ^= 1;
  }
}

// ---------------------------------------------------------------------------
// fp32 -> f16 convert: x then Wk,Wq,Wv into contiguous [xh | wh];
// last 8 blocks zero rsum (8192 floats).
// ---------------------------------------------------------------------------
__global__ void cvt_kernel(const float* __restrict__ x,
                           const float* __restrict__ w0,
                           const float* __restrict__ w1,
                           const float* __restrict__ w2,
                           unsigned short* __restrict__ dst,
                           float* __restrict__ rsum) {
  int i = blockIdx.x * 256 + threadIdx.x;
  if (i >= 2883584) {
    int z2 = i - 2883584;
    float4 z = {0.f, 0.f, 0.f, 0.f};
    ((float4*)rsum)[z2] = z;
    return;
  }
  const float* s;
  size_t si;
  if (i < 2097152) {
    s = x; si = i;
  } else {
    int j = i - 2097152;
    int z = j >> 18;
    s = (z == 0) ? w0 : ((z == 1) ? w1 : w2);
    si = j & 262143;
  }
  float4 f = ((const float4*)s)[si];
  ushort4 u;
  u.x = f2h(f.x); u.y = f2h(f.y); u.z = f2h(f.z); u.w = f2h(f.w);
  ((ushort4*)dst)[i] = u;
}

// ---------------------------------------------------------------------------
// QKV projection: dst[m,f] = sum_e xh[m,e]*W[f,e] + bias[f]   (f16 out)
// grid (24, 64): x = z*8 + tn (z fast -> xh slab reused across all 24).
// ---------------------------------------------------------------------------
__global__ __launch_bounds__(256) void qkv_gemm_kernel(
    const unsigned short* __restrict__ xh, const unsigned short* __restrict__ wh,
    const float* __restrict__ bk, const float* __restrict__ bq,
    const float* __restrict__ bv, unsigned short* __restrict__ kh,
    unsigned short* __restrict__ qh, unsigned short* __restrict__ vh) {
  __shared__ unsigned short As[2 * 128 * 32], Bs[2 * 128 * 32];
  const int tn = blockIdx.x & 7, z = blockIdx.x >> 3;
  const unsigned short* W = wh + (size_t)z * 1048576;
  const float* bias = (z == 0) ? bk : ((z == 1) ? bq : bv);
  unsigned short* dst = (z == 0) ? kh : ((z == 1) ? qh : vh);
  const int tm = blockIdx.y;

  f32x4 acc[4][4];
  gemm128(xh + (size_t)tm * 128 * 1024, W + (size_t)tn * 128 * 1024,
          1024, 1024, 1024, As, Bs, acc);

  const int lane = threadIdx.x & 63, wave = threadIdx.x >> 6;
  const int wm = wave >> 1, wn = wave & 1, rr = lane & 15, qq = lane >> 4;
  float bj[4];
#pragma unroll
  for (int j = 0; j < 4; ++j)
    bj[j] = bias[tn * 128 + wn * 64 + j * 16 + rr];
#pragma unroll
  for (int i = 0; i < 4; ++i)
#pragma unroll
    for (int reg = 0; reg < 4; ++reg) {
      int gm = tm * 128 + wm * 64 + i * 16 + qq * 4 + reg;
#pragma unroll
      for (int j = 0; j < 4; ++j) {
        int gc = tn * 128 + wn * 64 + j * 16 + rr;
        dst[(size_t)gm * 1024 + gc] = f2h(acc[i][j][reg] + bj[j]);
      }
    }
}

// ---------------------------------------------------------------------------
// v[b,t,d] -> vT[b,d,t]  (f16), 64x64 tiles, ushort4 vectorized
// ---------------------------------------------------------------------------
__global__ __launch_bounds__(256) void transpose_v_kernel(
    const unsigned short* __restrict__ v, unsigned short* __restrict__ vT) {
  __shared__ unsigned short tile[64][65];
  const int b = blockIdx.z;
  const unsigned short* vp = v + (size_t)b * 2048 * 1024;
  unsigned short* vtp = vT + (size_t)b * 1024 * 2048;
  const int t0 = blockIdx.x * 64, d0 = blockIdx.y * 64;
  const int lr = threadIdx.x >> 4, lc = (threadIdx.x & 15) * 4;
#pragma unroll
  for (int p = 0; p < 4; ++p) {
    int tr = p * 16 + lr;
    ushort4 u = *(const ushort4*)(vp + (size_t)(t0 + tr) * 1024 + d0 + lc);
    tile[tr][lc] = u.x; tile[tr][lc + 1] = u.y;
    tile[tr][lc + 2] = u.z; tile[tr][lc + 3] = u.w;
  }
  __syncthreads();
#pragma unroll
  for (int p = 0; p < 4; ++p) {
    int dr = p * 16 + lr;
    ushort4 u;
    u.x = tile[lc][dr]; u.y = tile[lc + 1][dr];
    u.z = tile[lc + 2][dr]; u.w = tile[lc + 3][dr];
    *(ushort4*)(vtp + (size_t)(d0 + dr) * 2048 + t0 + lc) = u;
  }
}

// ---------------------------------------------------------------------------
// scores (64x64 tiles): P[b,s,t] = exp(k[s].q[t]/32 - 4) for t<=s else 0,
// fused row-sum atomics. Triangular grid: 528 tiles/batch over 32 s-tiles.
// ---------------------------------------------------------------------------
__global__ __launch_bounds__(256) void scores_kernel(
    const unsigned short* __restrict__ kh, const unsigned short* __restrict__ qh,
    unsigned short* __restrict__ P, float* __restrict__ rsum) {
  const int b = blockIdx.y;
  int idx = blockIdx.x;
  int ts = (int)((sqrtf(8.0f * idx + 1.0f) - 1.0f) * 0.5f);
  while ((ts + 1) * (ts + 2) / 2 <= idx) ++ts;
  while (ts * (ts + 1) / 2 > idx) --ts;
  const int tt = idx - ts * (ts + 1) / 2;
  __shared__ unsigned short As[2 * 64 * 32], Bs[2 * 64 * 32];

  f32x4 acc[2][2];
  gemm64(kh + ((size_t)(b * 2048 + ts * 64)) * 1024,
         qh + ((size_t)(b * 2048 + tt * 64)) * 1024,
         1024, 1024, 1024, As, Bs, acc);

  const int lane = threadIdx.x & 63, wave = threadIdx.x >> 6;
  const int wm = wave >> 1, wn = wave & 1, rr = lane & 15, qq = lane >> 4;
  unsigned short* Pb = P + (size_t)b * 2048 * 2048;
  float* rs = rsum + b * 2048;
#pragma unroll
  for (int i = 0; i < 2; ++i)
#pragma unroll
    for (int reg = 0; reg < 4; ++reg) {
      int srow = ts * 64 + wm * 32 + i * 16 + qq * 4 + reg;
      float p = 0.f;
#pragma unroll
      for (int j = 0; j < 2; ++j) {
        int tcol = tt * 64 + wn * 32 + j * 16 + rr;
        float e = (tcol <= srow) ? __expf(acc[i][j][reg] * 0.03125f - 4.0f)
                                 : 0.0f;
        Pb[(size_t)srow * 2048 + tcol] = f2h(e);
        p += e;
      }
#pragma unroll
      for (int off = 1; off < 16; off <<= 1) p += __shfl_xor(p, off);
      if (rr == 0) atomicAdd(rs + srow, p);
    }
}

// ---------------------------------------------------------------------------
// pv (64x64 tiles): out[b,s,d] = (1/rsum) * sum_t P[b,s,t] * vT[b,d,t].
// grid (16,32,4); K truncated to (ts+1)*64 (P written only there);
// y reversed (big-K first for tail balance).
// ---------------------------------------------------------------------------
__global__ __launch_bounds__(256) void pv_gemm_kernel(
    const unsigned short* __restrict__ P, const unsigned short* __restrict__ vT,
    const float* __restrict__ rsum, float* __restrict__ out) {
  const int td = blockIdx.x, ts = 31 - blockIdx.y, b = blockIdx.z;
  __shared__ unsigned short As[2 * 64 * 32], Bs[2 * 64 * 32];

  f32x4 acc[2][2];
  gemm64(P + ((size_t)(b * 2048 + ts * 64)) * 2048,
         vT + ((size_t)(b * 1024 + td * 64)) * 2048,
         2048, 2048, (ts + 1) * 64, As, Bs, acc);

  const int lane = threadIdx.x & 63, wave = threadIdx.x >> 6;
  const int wm = wave >> 1, wn = wave & 1, rr = lane & 15, qq = lane >> 4;
#pragma unroll
  for (int i = 0; i < 2; ++i)
#pragma unroll
    for (int reg = 0; reg < 4; ++reg) {
      int srow = ts * 64 + wm * 32 + i * 16 + qq * 4 + reg;
      float rv = __builtin_amdgcn_rcpf(rsum[b * 2048 + srow]);
#pragma unroll
      for (int j = 0; j < 2; ++j) {
        int dcol = td * 64 + wn * 32 + j * 16 + rr;
        out[((size_t)(b * 2048 + srow)) * 1024 + dcol] = acc[i][j][reg] * rv;
      }
    }
}

// ---------------------------------------------------------------------------
// launch
// ---------------------------------------------------------------------------
extern "C" void kernel_launch(void* const* d_in, const int* in_sizes, int n_in,
                              void* d_out, int out_size, void* d_ws,
                              size_t ws_size, hipStream_t stream) {
  const float* x  = (const float*)d_in[0];
  const float* Wk = (const float*)d_in[1];
  const float* bk = (const float*)d_in[2];
  const float* Wq = (const float*)d_in[3];
  const float* bq = (const float*)d_in[4];
  const float* Wv = (const float*)d_in[5];
  const float* bv = (const float*)d_in[6];
  float* out = (float*)d_out;

  char* ws = (char*)d_ws;
  const size_t MB = 1ull << 20;
  // Aliased layout (86 MB + 32 KB): P overlays xh/wh/vh (dead by scores).
  unsigned short* xh = (unsigned short*)(ws + 0);        // 16 MB  [0,16)
  unsigned short* wh = (unsigned short*)(ws + 16 * MB);  //  6 MB  [16,22)
  unsigned short* vh = (unsigned short*)(ws + 22 * MB);  // 16 MB  [22,38)
  unsigned short* P  = (unsigned short*)(ws + 0);        // 32 MB  [0,32) alias
  unsigned short* kh = (unsigned short*)(ws + 38 * MB);  // 16 MB  [38,54)
  unsigned short* qh = (unsigned short*)(ws + 54 * MB);  // 16 MB  [54,70)
  unsigned short* vT = (unsigned short*)(ws + 70 * MB);  // 16 MB  [70,86)
  float* rsum = (float*)(ws + 86 * MB);                  // 32 KB

  // 1) converts (x + 3 W) + rsum zero-init (last 8 blocks)
  cvt_kernel<<<11272, 256, 0, stream>>>(x, Wk, Wq, Wv, xh, rsum);
  // 2) QKV projections (f16)
  qkv_gemm_kernel<<<dim3(24, 64), 256, 0, stream>>>(xh, wh, bk, bq, bv,
                                                    kh, qh, vh);
  // 3) v -> vT (vectorized)
  transpose_v_kernel<<<dim3(32, 16, 4), 256, 0, stream>>>(vh, vT);
  // 4) masked exp(scores) + fused row-sum atomics (64x64 triangular grid)
  scores_kernel<<<dim3(528, 4), 256, 0, stream>>>(kh, qh, P, rsum);
  // 5) (P @ v) * (1/rsum) -> out (64x64 tiles)
  pv_gemm_kernel<<<dim3(16, 32, 4), 256, 0, stream>>>(P, vT, rsum, out);
}

// Round 7
// 256.278 us; speedup vs baseline: 1.3469x; 1.1052x over previous
//
#include <hip/hip_runtime.h>
#include <cstdint>

// ---------------------------------------------------------------------------
// DefaultAttention: x[4,2048,1024] fp32; k=xWk^T+bk, q=xWq^T+bq, v=xWv^T+bv;
// sim = k q^T / 32 (causal tril), attn = softmax(sim), out = attn @ v (fp32).
// R7: back to R4 base (best verified). qkv z=2 writes vT directly (packed
// ushort4) -> transpose kernel deleted. scores/pv switch to single-buffer
// 16KB LDS + __launch_bounds__(256,4) for ~4 blocks/CU in their single-round
// regime (they were ramp+drain-bound at 2.3 blocks/CU).
// ---------------------------------------------------------------------------

typedef __attribute__((ext_vector_type(8))) _Float16 f16x8;
typedef __attribute__((ext_vector_type(4))) float f32x4;

__device__ __forceinline__ unsigned short f2h(float x) {
  return __builtin_bit_cast(unsigned short, (_Float16)x);
}

// async global->LDS, 16B per lane; LDS dest = wave-uniform base + lane*16
__device__ __forceinline__ void lds_dma16(const void* g, void* l) {
  auto gp = reinterpret_cast<const __attribute__((address_space(1))) void*>(
      reinterpret_cast<uintptr_t>(g));
  auto lp = reinterpret_cast<__attribute__((address_space(3))) void*>(
      reinterpret_cast<uintptr_t>(l));
  __builtin_amdgcn_global_load_lds(gp, lp, 16, 0, 0);
}

// ---------------------------------------------------------------------------
// gemm128 (dbuf): C[128x128] += A[128xK] * B[128xK]^T. BK=32, XOR-swizzled
// LDS (conflict-free), double-buffered single-barrier pipeline (R4-verified).
// 32 KB LDS -> ~2.3 blocks/CU; best for multi-round launches (qkv).
// ---------------------------------------------------------------------------
__device__ __forceinline__ void gemm128(const unsigned short* __restrict__ Ag,
                                        const unsigned short* __restrict__ Bg,
                                        int lda, int ldb, int nk,
                                        unsigned short* As, unsigned short* Bs,
                                        f32x4 acc[4][4]) {
  const int tid = threadIdx.x;
  const int lane = tid & 63, wave = tid >> 6;
  const int wm = wave >> 1, wn = wave & 1;
  const int sr = lane >> 2;                               // staging row in chunk
  const int scb = (((lane & 3) ^ ((lane >> 3) & 3)) * 8); // swizzled src col
  const int rr = lane & 15, qq = lane >> 4;
  const int slot = ((qq ^ ((rr >> 1) & 3)) * 8);          // swizzled read col

#pragma unroll
  for (int i = 0; i < 4; ++i)
#pragma unroll
    for (int j = 0; j < 4; ++j) {
      f32x4 z = {0.f, 0.f, 0.f, 0.f};
      acc[i][j] = z;
    }

#pragma unroll
  for (int c = 0; c < 2; ++c) {
    int chunk = wave * 2 + c;
    int row = chunk * 16 + sr;
    lds_dma16(Ag + (size_t)row * lda + scb, As + chunk * 512);
    lds_dma16(Bg + (size_t)row * ldb + scb, Bs + chunk * 512);
  }

  int buf = 0;
  for (int k0 = 0; k0 < nk; k0 += 32) {
    __syncthreads();  // drains staging issued one compute-phase ago
    const int kn = k0 + 32;
    if (kn < nk) {
      unsigned short* An = As + (buf ^ 1) * 4096;
      unsigned short* Bn = Bs + (buf ^ 1) * 4096;
#pragma unroll
      for (int c = 0; c < 2; ++c) {
        int chunk = wave * 2 + c;
        int row = chunk * 16 + sr;
        lds_dma16(Ag + (size_t)row * lda + kn + scb, An + chunk * 512);
        lds_dma16(Bg + (size_t)row * ldb + kn + scb, Bn + chunk * 512);
      }
    }

    f16x8 af[4], bf[4];
    const unsigned short* Ar = As + buf * 4096 + (wm * 64 + rr) * 32 + slot;
    const unsigned short* Br = Bs + buf * 4096 + (wn * 64 + rr) * 32 + slot;
#pragma unroll
    for (int i = 0; i < 4; ++i) af[i] = *(const f16x8*)(Ar + i * 512);
#pragma unroll
    for (int j = 0; j < 4; ++j) bf[j] = *(const f16x8*)(Br + j * 512);
#pragma unroll
    for (int i = 0; i < 4; ++i)
#pragma unroll
      for (int j = 0; j < 4; ++j)
        acc[i][j] = __builtin_amdgcn_mfma_f32_16x16x32_f16(af[i], bf[j],
                                                           acc[i][j], 0, 0, 0);
    buf ^= 1;
  }
}

// ---------------------------------------------------------------------------
// gemm128_sb (single-buffer): same math, 16 KB LDS, classic 2-barrier loop.
// For single-round launches where co-residency > per-iter pipelining.
// ---------------------------------------------------------------------------
__device__ __forceinline__ void gemm128_sb(
    const unsigned short* __restrict__ Ag, const unsigned short* __restrict__ Bg,
    int lda, int ldb, int nk, unsigned short* As, unsigned short* Bs,
    f32x4 acc[4][4]) {
  const int tid = threadIdx.x;
  const int lane = tid & 63, wave = tid >> 6;
  const int wm = wave >> 1, wn = wave & 1;
  const int sr = lane >> 2;
  const int scb = (((lane & 3) ^ ((lane >> 3) & 3)) * 8);
  const int rr = lane & 15, qq = lane >> 4;
  const int slot = ((qq ^ ((rr >> 1) & 3)) * 8);

#pragma unroll
  for (int i = 0; i < 4; ++i)
#pragma unroll
    for (int j = 0; j < 4; ++j) {
      f32x4 z = {0.f, 0.f, 0.f, 0.f};
      acc[i][j] = z;
    }

  for (int k0 = 0; k0 < nk; k0 += 32) {
#pragma unroll
    for (int c = 0; c < 2; ++c) {
      int chunk = wave * 2 + c;
      int row = chunk * 16 + sr;
      lds_dma16(Ag + (size_t)row * lda + k0 + scb, As + chunk * 512);
      lds_dma16(Bg + (size_t)row * ldb + k0 + scb, Bs + chunk * 512);
    }
    __syncthreads();

    f16x8 af[4], bf[4];
    const unsigned short* Ar = As + (wm * 64 + rr) * 32 + slot;
    const unsigned short* Br = Bs + (wn * 64 + rr) * 32 + slot;
#pragma unroll
    for (int i = 0; i < 4; ++i) af[i] = *(const f16x8*)(Ar + i * 512);
#pragma unroll
    for (int j = 0; j < 4; ++j) bf[j] = *(const f16x8*)(Br + j * 512);
#pragma unroll
    for (int i = 0; i < 4; ++i)
#pragma unroll
      for (int j = 0; j < 4; ++j)
        acc[i][j] = __builtin_amdgcn_mfma_f32_16x16x32_f16(af[i], bf[j],
                                                           acc[i][j], 0, 0, 0);
    __syncthreads();
  }
}

// ---------------------------------------------------------------------------
// fp32 -> f16 convert: x then Wk,Wq,Wv into contiguous [xh | wh];
// last 8 blocks zero rsum (8192 floats).
// ---------------------------------------------------------------------------
__global__ void cvt_kernel(const float* __restrict__ x,
                           const float* __restrict__ w0,
                           const float* __restrict__ w1,
                           const float* __restrict__ w2,
                           unsigned short* __restrict__ dst,
                           float* __restrict__ rsum) {
  int i = blockIdx.x * 256 + threadIdx.x;
  if (i >= 2883584) {
    int z2 = i - 2883584;
    float4 z = {0.f, 0.f, 0.f, 0.f};
    ((float4*)rsum)[z2] = z;
    return;
  }
  const float* s;
  size_t si;
  if (i < 2097152) {
    s = x; si = i;
  } else {
    int j = i - 2097152;
    int z = j >> 18;
    s = (z == 0) ? w0 : ((z == 1) ? w1 : w2);
    si = j & 262143;
  }
  float4 f = ((const float4*)s)[si];
  ushort4 u;
  u.x = f2h(f.x); u.y = f2h(f.y); u.z = f2h(f.z); u.w = f2h(f.w);
  ((ushort4*)dst)[i] = u;
}

// ---------------------------------------------------------------------------
// QKV projection. z=0 -> kh[m,f], z=1 -> qh[m,f], z=2 -> vT[b,d,t] directly
// (4 consecutive t per lane = one ushort4 store; kills the transpose pass).
// grid (24, 64): x = z*8 + tn (z fast -> xh slab reused across all 24).
// ---------------------------------------------------------------------------
__global__ __launch_bounds__(256) void qkv_gemm_kernel(
    const unsigned short* __restrict__ xh, const unsigned short* __restrict__ wh,
    const float* __restrict__ bk, const float* __restrict__ bq,
    const float* __restrict__ bv, unsigned short* __restrict__ kh,
    unsigned short* __restrict__ qh, unsigned short* __restrict__ vT) {
  __shared__ unsigned short As[2 * 128 * 32], Bs[2 * 128 * 32];
  const int tn = blockIdx.x & 7, z = blockIdx.x >> 3;
  const unsigned short* W = wh + (size_t)z * 1048576;
  const float* bias = (z == 0) ? bk : ((z == 1) ? bq : bv);
  const int tm = blockIdx.y;

  f32x4 acc[4][4];
  gemm128(xh + (size_t)tm * 128 * 1024, W + (size_t)tn * 128 * 1024,
          1024, 1024, 1024, As, Bs, acc);

  const int lane = threadIdx.x & 63, wave = threadIdx.x >> 6;
  const int wm = wave >> 1, wn = wave & 1, rr = lane & 15, qq = lane >> 4;
  float bj[4];
#pragma unroll
  for (int j = 0; j < 4; ++j)
    bj[j] = bias[tn * 128 + wn * 64 + j * 16 + rr];

  if (z == 2) {
    // vT[b][d][t]: d = col, t = row; 4 regs = 4 consecutive t -> ushort4
#pragma unroll
    for (int i = 0; i < 4; ++i) {
      int gm0 = tm * 128 + wm * 64 + i * 16 + qq * 4;  // global row (b,t)
      int bb = gm0 >> 11, t0 = gm0 & 2047;
#pragma unroll
      for (int j = 0; j < 4; ++j) {
        int gc = tn * 128 + wn * 64 + j * 16 + rr;     // d
        ushort4 u;
        u.x = f2h(acc[i][j][0] + bj[j]);
        u.y = f2h(acc[i][j][1] + bj[j]);
        u.z = f2h(acc[i][j][2] + bj[j]);
        u.w = f2h(acc[i][j][3] + bj[j]);
        *(ushort4*)(vT + ((size_t)(bb * 1024 + gc)) * 2048 + t0) = u;
      }
    }
  } else {
    unsigned short* dst = (z == 0) ? kh : qh;
#pragma unroll
    for (int i = 0; i < 4; ++i)
#pragma unroll
      for (int reg = 0; reg < 4; ++reg) {
        int gm = tm * 128 + wm * 64 + i * 16 + qq * 4 + reg;
#pragma unroll
        for (int j = 0; j < 4; ++j) {
          int gc = tn * 128 + wn * 64 + j * 16 + rr;
          dst[(size_t)gm * 1024 + gc] = f2h(acc[i][j][reg] + bj[j]);
        }
      }
  }
}

// ---------------------------------------------------------------------------
// scores: P[b,s,t] = exp(k[s].q[t]/32 - 4) for t<=s else 0  (f16), plus
// fused row-sum atomics. Triangular grid (136,4). Single-buffer, 4 blk/CU.
// ---------------------------------------------------------------------------
__global__ __launch_bounds__(256, 4) void scores_kernel(
    const unsigned short* __restrict__ kh, const unsigned short* __restrict__ qh,
    unsigned short* __restrict__ P, float* __restrict__ rsum) {
  const int b = blockIdx.y;
  int idx = blockIdx.x;
  int ts = (int)((sqrtf(8.0f * idx + 1.0f) - 1.0f) * 0.5f);
  while ((ts + 1) * (ts + 2) / 2 <= idx) ++ts;
  while (ts * (ts + 1) / 2 > idx) --ts;
  const int tt = idx - ts * (ts + 1) / 2;
  __shared__ unsigned short As[128 * 32], Bs[128 * 32];

  f32x4 acc[4][4];
  gemm128_sb(kh + ((size_t)(b * 2048 + ts * 128)) * 1024,
             qh + ((size_t)(b * 2048 + tt * 128)) * 1024,
             1024, 1024, 1024, As, Bs, acc);

  const int lane = threadIdx.x & 63, wave = threadIdx.x >> 6;
  const int wm = wave >> 1, wn = wave & 1, rr = lane & 15, qq = lane >> 4;
  unsigned short* Pb = P + (size_t)b * 2048 * 2048;
  float* rs = rsum + b * 2048;
#pragma unroll
  for (int i = 0; i < 4; ++i)
#pragma unroll
    for (int reg = 0; reg < 4; ++reg) {
      int srow = ts * 128 + wm * 64 + i * 16 + qq * 4 + reg;
      float p = 0.f;
#pragma unroll
      for (int j = 0; j < 4; ++j) {
        int tcol = tt * 128 + wn * 64 + j * 16 + rr;
        float e = (tcol <= srow) ? __expf(acc[i][j][reg] * 0.03125f - 4.0f)
                                 : 0.0f;
        Pb[(size_t)srow * 2048 + tcol] = f2h(e);
        p += e;
      }
#pragma unroll
      for (int off = 1; off < 16; off <<= 1) p += __shfl_xor(p, off);
      if (rr == 0) atomicAdd(rs + srow, p);
    }
}

// ---------------------------------------------------------------------------
// out[b,s,d] = (1/rsum[b,s]) * sum_t P[b,s,t] * vT[b,d,t]   (fp32 out)
// grid (8,16,4); K truncated to (ts+1)*128; y reversed. Single-buffer.
// ---------------------------------------------------------------------------
__global__ __launch_bounds__(256, 4) void pv_gemm_kernel(
    const unsigned short* __restrict__ P, const unsigned short* __restrict__ vT,
    const float* __restrict__ rsum, float* __restrict__ out) {
  const int td = blockIdx.x, ts = 15 - blockIdx.y, b = blockIdx.z;
  __shared__ unsigned short As[128 * 32], Bs[128 * 32];

  f32x4 acc[4][4];
  gemm128_sb(P + ((size_t)(b * 2048 + ts * 128)) * 2048,
             vT + ((size_t)(b * 1024 + td * 128)) * 2048,
             2048, 2048, (ts + 1) * 128, As, Bs, acc);

  const int lane = threadIdx.x & 63, wave = threadIdx.x >> 6;
  const int wm = wave >> 1, wn = wave & 1, rr = lane & 15, qq = lane >> 4;
#pragma unroll
  for (int i = 0; i < 4; ++i)
#pragma unroll
    for (int reg = 0; reg < 4; ++reg) {
      int srow = ts * 128 + wm * 64 + i * 16 + qq * 4 + reg;
      float rv = __builtin_amdgcn_rcpf(rsum[b * 2048 + srow]);
#pragma unroll
      for (int j = 0; j < 4; ++j) {
        int dcol = td * 128 + wn * 64 + j * 16 + rr;
        out[((size_t)(b * 2048 + srow)) * 1024 + dcol] = acc[i][j][reg] * rv;
      }
    }
}

// ---------------------------------------------------------------------------
// launch
// ---------------------------------------------------------------------------
extern "C" void kernel_launch(void* const* d_in, const int* in_sizes, int n_in,
                              void* d_out, int out_size, void* d_ws,
                              size_t ws_size, hipStream_t stream) {
  const float* x  = (const float*)d_in[0];
  const float* Wk = (const float*)d_in[1];
  const float* bk = (const float*)d_in[2];
  const float* Wq = (const float*)d_in[3];
  const float* bq = (const float*)d_in[4];
  const float* Wv = (const float*)d_in[5];
  const float* bv = (const float*)d_in[6];
  float* out = (float*)d_out;

  char* ws = (char*)d_ws;
  const size_t MB = 1ull << 20;
  // Aliased layout (86 MB + 32 KB): P overlays xh/wh (dead by scores).
  unsigned short* xh = (unsigned short*)(ws + 0);        // 16 MB  [0,16)
  unsigned short* wh = (unsigned short*)(ws + 16 * MB);  //  6 MB  [16,22)
  unsigned short* P  = (unsigned short*)(ws + 0);        // 32 MB  [0,32) alias
  unsigned short* kh = (unsigned short*)(ws + 38 * MB);  // 16 MB  [38,54)
  unsigned short* qh = (unsigned short*)(ws + 54 * MB);  // 16 MB  [54,70)
  unsigned short* vT = (unsigned short*)(ws + 70 * MB);  // 16 MB  [70,86)
  float* rsum = (float*)(ws + 86 * MB);                  // 32 KB

  // 1) converts (x + 3 W) + rsum zero-init (last 8 blocks)
  cvt_kernel<<<11272, 256, 0, stream>>>(x, Wk, Wq, Wv, xh, rsum);
  // 2) QKV projections; z=2 writes vT directly (no transpose pass)
  qkv_gemm_kernel<<<dim3(24, 64), 256, 0, stream>>>(xh, wh, bk, bq, bv,
                                                    kh, qh, vT);
  // 3) masked exp(scores) + fused row-sum atomics (triangular grid)
  scores_kernel<<<dim3(136, 4), 256, 0, stream>>>(kh, qh, P, rsum);
  // 4) (P @ v) * (1/rsum) -> out
  pv_gemm_kernel<<<dim3(8, 16, 4), 256, 0, stream>>>(P, vT, rsum, out);
}

// Round 8
// 245.835 us; speedup vs baseline: 1.4041x; 1.0425x over previous
//
#include <hip/hip_runtime.h>
#include <cstdint>

// ---------------------------------------------------------------------------
// DefaultAttention: x[4,2048,1024] fp32; k=xWk^T+bk, q=xWq^T+bq, v=xWv^T+bv;
// sim = k q^T / 32 (causal tril), attn = softmax(sim), out = attn @ v (fp32).
// R8: R4 dbuf gemm128 everywhere (verified best). v-projection computed
// operand-swapped (A=Wv rows=d, B=xh rows=t) so the standard coalesced
// C-epilogue writes vT[b][d][t] directly -> transpose pass eliminated with
// no VGPR bloat (R7's scatter-store cost 20 VGPR).
// ---------------------------------------------------------------------------

typedef __attribute__((ext_vector_type(8))) _Float16 f16x8;
typedef __attribute__((ext_vector_type(4))) float f32x4;

__device__ __forceinline__ unsigned short f2h(float x) {
  return __builtin_bit_cast(unsigned short, (_Float16)x);
}

// async global->LDS, 16B per lane; LDS dest = wave-uniform base + lane*16
__device__ __forceinline__ void lds_dma16(const void* g, void* l) {
  auto gp = reinterpret_cast<const __attribute__((address_space(1))) void*>(
      reinterpret_cast<uintptr_t>(g));
  auto lp = reinterpret_cast<__attribute__((address_space(3))) void*>(
      reinterpret_cast<uintptr_t>(l));
  __builtin_amdgcn_global_load_lds(gp, lp, 16, 0, 0);
}

// ---------------------------------------------------------------------------
// gemm128 (dbuf): C[128x128] += A[128xK] * B[128xK]^T. BK=32, XOR-swizzled
// LDS (conflict-free), double-buffered single-barrier pipeline (R4-verified).
// ---------------------------------------------------------------------------
__device__ __forceinline__ void gemm128(const unsigned short* __restrict__ Ag,
                                        const unsigned short* __restrict__ Bg,
                                        int lda, int ldb, int nk,
                                        unsigned short* As, unsigned short* Bs,
                                        f32x4 acc[4][4]) {
  const int tid = threadIdx.x;
  const int lane = tid & 63, wave = tid >> 6;
  const int wm = wave >> 1, wn = wave & 1;
  const int sr = lane >> 2;                               // staging row in chunk
  const int scb = (((lane & 3) ^ ((lane >> 3) & 3)) * 8); // swizzled src col
  const int rr = lane & 15, qq = lane >> 4;
  const int slot = ((qq ^ ((rr >> 1) & 3)) * 8);          // swizzled read col

#pragma unroll
  for (int i = 0; i < 4; ++i)
#pragma unroll
    for (int j = 0; j < 4; ++j) {
      f32x4 z = {0.f, 0.f, 0.f, 0.f};
      acc[i][j] = z;
    }

#pragma unroll
  for (int c = 0; c < 2; ++c) {
    int chunk = wave * 2 + c;
    int row = chunk * 16 + sr;
    lds_dma16(Ag + (size_t)row * lda + scb, As + chunk * 512);
    lds_dma16(Bg + (size_t)row * ldb + scb, Bs + chunk * 512);
  }

  int buf = 0;
  for (int k0 = 0; k0 < nk; k0 += 32) {
    __syncthreads();  // drains staging issued one compute-phase ago
    const int kn = k0 + 32;
    if (kn < nk) {
      unsigned short* An = As + (buf ^ 1) * 4096;
      unsigned short* Bn = Bs + (buf ^ 1) * 4096;
#pragma unroll
      for (int c = 0; c < 2; ++c) {
        int chunk = wave * 2 + c;
        int row = chunk * 16 + sr;
        lds_dma16(Ag + (size_t)row * lda + kn + scb, An + chunk * 512);
        lds_dma16(Bg + (size_t)row * ldb + kn + scb, Bn + chunk * 512);
      }
    }

    f16x8 af[4], bf[4];
    const unsigned short* Ar = As + buf * 4096 + (wm * 64 + rr) * 32 + slot;
    const unsigned short* Br = Bs + buf * 4096 + (wn * 64 + rr) * 32 + slot;
#pragma unroll
    for (int i = 0; i < 4; ++i) af[i] = *(const f16x8*)(Ar + i * 512);
#pragma unroll
    for (int j = 0; j < 4; ++j) bf[j] = *(const f16x8*)(Br + j * 512);
#pragma unroll
    for (int i = 0; i < 4; ++i)
#pragma unroll
      for (int j = 0; j < 4; ++j)
        acc[i][j] = __builtin_amdgcn_mfma_f32_16x16x32_f16(af[i], bf[j],
                                                           acc[i][j], 0, 0, 0);
    buf ^= 1;
  }
}

// ---------------------------------------------------------------------------
// fp32 -> f16 convert: x then Wk,Wq,Wv into contiguous [xh | wh];
// last 8 blocks zero rsum (8192 floats).
// ---------------------------------------------------------------------------
__global__ void cvt_kernel(const float* __restrict__ x,
                           const float* __restrict__ w0,
                           const float* __restrict__ w1,
                           const float* __restrict__ w2,
                           unsigned short* __restrict__ dst,
                           float* __restrict__ rsum) {
  int i = blockIdx.x * 256 + threadIdx.x;
  if (i >= 2883584) {
    int z2 = i - 2883584;
    float4 z = {0.f, 0.f, 0.f, 0.f};
    ((float4*)rsum)[z2] = z;
    return;
  }
  const float* s;
  size_t si;
  if (i < 2097152) {
    s = x; si = i;
  } else {
    int j = i - 2097152;
    int z = j >> 18;
    s = (z == 0) ? w0 : ((z == 1) ? w1 : w2);
    si = j & 262143;
  }
  float4 f = ((const float4*)s)[si];
  ushort4 u;
  u.x = f2h(f.x); u.y = f2h(f.y); u.z = f2h(f.z); u.w = f2h(f.w);
  ((ushort4*)dst)[i] = u;
}

// ---------------------------------------------------------------------------
// QKV projection, grid (24, 64): x = z*8 + tn (z fast -> xh slab shared by
// all 24 blocks of a tm), y = tm.
//   z=0/1: C[t, f] = xh[t-slab] . W[f-tile]^T  -> kh/qh[t*1024 + f]
//   z=2  : C[d, t] = Wv[d-tile] . xh[t-slab]^T -> vT[b][d][t]  (direct;
//          row-bias bv[d], standard coalesced epilogue, no transpose pass)
// ---------------------------------------------------------------------------
__global__ __launch_bounds__(256) void qkv_gemm_kernel(
    const unsigned short* __restrict__ xh, const unsigned short* __restrict__ wh,
    const float* __restrict__ bk, const float* __restrict__ bq,
    const float* __restrict__ bv, unsigned short* __restrict__ kh,
    unsigned short* __restrict__ qh, unsigned short* __restrict__ vT) {
  __shared__ unsigned short As[2 * 128 * 32], Bs[2 * 128 * 32];
  const int tn = blockIdx.x & 7, z = blockIdx.x >> 3;
  const unsigned short* W = wh + (size_t)z * 1048576;
  const int tm = blockIdx.y;

  const unsigned short* Ag = (z == 2) ? (W + (size_t)tn * 128 * 1024)
                                      : (xh + (size_t)tm * 128 * 1024);
  const unsigned short* Bg = (z == 2) ? (xh + (size_t)tm * 128 * 1024)
                                      : (W + (size_t)tn * 128 * 1024);

  f32x4 acc[4][4];
  gemm128(Ag, Bg, 1024, 1024, 1024, As, Bs, acc);

  const int lane = threadIdx.x & 63, wave = threadIdx.x >> 6;
  const int wm = wave >> 1, wn = wave & 1, rr = lane & 15, qq = lane >> 4;

  if (z == 2) {
    // rows = d, cols = t; bias is per-row (float4 over reg)
#pragma unroll
    for (int i = 0; i < 4; ++i) {
      int d0 = tn * 128 + wm * 64 + i * 16 + qq * 4;
      float4 bi = *(const float4*)(bv + d0);
      float bir[4] = {bi.x, bi.y, bi.z, bi.w};
#pragma unroll
      for (int reg = 0; reg < 4; ++reg) {
        int d = d0 + reg;
#pragma unroll
        for (int j = 0; j < 4; ++j) {
          int tg = tm * 128 + wn * 64 + j * 16 + rr;  // global token
          int bb = tg >> 11, tt = tg & 2047;
          vT[((size_t)(bb * 1024 + d)) * 2048 + tt] =
              f2h(acc[i][j][reg] + bir[reg]);
        }
      }
    }
  } else {
    const float* bias = (z == 0) ? bk : bq;
    unsigned short* dst = (z == 0) ? kh : qh;
    float bj[4];
#pragma unroll
    for (int j = 0; j < 4; ++j)
      bj[j] = bias[tn * 128 + wn * 64 + j * 16 + rr];
#pragma unroll
    for (int i = 0; i < 4; ++i)
#pragma unroll
      for (int reg = 0; reg < 4; ++reg) {
        int gm = tm * 128 + wm * 64 + i * 16 + qq * 4 + reg;
#pragma unroll
        for (int j = 0; j < 4; ++j) {
          int gc = tn * 128 + wn * 64 + j * 16 + rr;
          dst[(size_t)gm * 1024 + gc] = f2h(acc[i][j][reg] + bj[j]);
        }
      }
  }
}

// ---------------------------------------------------------------------------
// scores: P[b,s,t] = exp(k[s].q[t]/32 - 4) for t<=s else 0  (f16), plus
// fused row-sum atomics. Triangular grid (136,4). Dbuf pipeline.
// ---------------------------------------------------------------------------
__global__ __launch_bounds__(256) void scores_kernel(
    const unsigned short* __restrict__ kh, const unsigned short* __restrict__ qh,
    unsigned short* __restrict__ P, float* __restrict__ rsum) {
  const int b = blockIdx.y;
  int idx = blockIdx.x;
  int ts = (int)((sqrtf(8.0f * idx + 1.0f) - 1.0f) * 0.5f);
  while ((ts + 1) * (ts + 2) / 2 <= idx) ++ts;
  while (ts * (ts + 1) / 2 > idx) --ts;
  const int tt = idx - ts * (ts + 1) / 2;
  __shared__ unsigned short As[2 * 128 * 32], Bs[2 * 128 * 32];

  f32x4 acc[4][4];
  gemm128(kh + ((size_t)(b * 2048 + ts * 128)) * 1024,
          qh + ((size_t)(b * 2048 + tt * 128)) * 1024,
          1024, 1024, 1024, As, Bs, acc);

  const int lane = threadIdx.x & 63, wave = threadIdx.x >> 6;
  const int wm = wave >> 1, wn = wave & 1, rr = lane & 15, qq = lane >> 4;
  unsigned short* Pb = P + (size_t)b * 2048 * 2048;
  float* rs = rsum + b * 2048;
#pragma unroll
  for (int i = 0; i < 4; ++i)
#pragma unroll
    for (int reg = 0; reg < 4; ++reg) {
      int srow = ts * 128 + wm * 64 + i * 16 + qq * 4 + reg;
      float p = 0.f;
#pragma unroll
      for (int j = 0; j < 4; ++j) {
        int tcol = tt * 128 + wn * 64 + j * 16 + rr;
        float e = (tcol <= srow) ? __expf(acc[i][j][reg] * 0.03125f - 4.0f)
                                 : 0.0f;
        Pb[(size_t)srow * 2048 + tcol] = f2h(e);
        p += e;
      }
#pragma unroll
      for (int off = 1; off < 16; off <<= 1) p += __shfl_xor(p, off);
      if (rr == 0) atomicAdd(rs + srow, p);
    }
}

// ---------------------------------------------------------------------------
// out[b,s,d] = (1/rsum[b,s]) * sum_t P[b,s,t] * vT[b,d,t]   (fp32 out)
// grid (8,16,4); K truncated to (ts+1)*128; y reversed (big-K first).
// ---------------------------------------------------------------------------
__global__ __launch_bounds__(256) void pv_gemm_kernel(
    const unsigned short* __restrict__ P, const unsigned short* __restrict__ vT,
    const float* __restrict__ rsum, float* __restrict__ out) {
  const int td = blockIdx.x, ts = 15 - blockIdx.y, b = blockIdx.z;
  __shared__ unsigned short As[2 * 128 * 32], Bs[2 * 128 * 32];

  f32x4 acc[4][4];
  gemm128(P + ((size_t)(b * 2048 + ts * 128)) * 2048,
          vT + ((size_t)(b * 1024 + td * 128)) * 2048,
          2048, 2048, (ts + 1) * 128, As, Bs, acc);

  const int lane = threadIdx.x & 63, wave = threadIdx.x >> 6;
  const int wm = wave >> 1, wn = wave & 1, rr = lane & 15, qq = lane >> 4;
#pragma unroll
  for (int i = 0; i < 4; ++i) {
    int s0 = ts * 128 + wm * 64 + i * 16 + qq * 4;
    float4 r4 = *(const float4*)(rsum + b * 2048 + s0);
    float rv[4] = {__builtin_amdgcn_rcpf(r4.x), __builtin_amdgcn_rcpf(r4.y),
                   __builtin_amdgcn_rcpf(r4.z), __builtin_amdgcn_rcpf(r4.w)};
#pragma unroll
    for (int reg = 0; reg < 4; ++reg) {
      int srow = s0 + reg;
#pragma unroll
      for (int j = 0; j < 4; ++j) {
        int dcol = td * 128 + wn * 64 + j * 16 + rr;
        out[((size_t)(b * 2048 + srow)) * 1024 + dcol] =
            acc[i][j][reg] * rv[reg];
      }
    }
  }
}

// ---------------------------------------------------------------------------
// launch
// ---------------------------------------------------------------------------
extern "C" void kernel_launch(void* const* d_in, const int* in_sizes, int n_in,
                              void* d_out, int out_size, void* d_ws,
                              size_t ws_size, hipStream_t stream) {
  const float* x  = (const float*)d_in[0];
  const float* Wk = (const float*)d_in[1];
  const float* bk = (const float*)d_in[2];
  const float* Wq = (const float*)d_in[3];
  const float* bq = (const float*)d_in[4];
  const float* Wv = (const float*)d_in[5];
  const float* bv = (const float*)d_in[6];
  float* out = (float*)d_out;

  char* ws = (char*)d_ws;
  const size_t MB = 1ull << 20;
  // Aliased layout (86 MB + 32 KB): P overlays xh/wh (dead by scores).
  unsigned short* xh = (unsigned short*)(ws + 0);        // 16 MB  [0,16)
  unsigned short* wh = (unsigned short*)(ws + 16 * MB);  //  6 MB  [16,22)
  unsigned short* P  = (unsigned short*)(ws + 0);        // 32 MB  [0,32) alias
  unsigned short* kh = (unsigned short*)(ws + 38 * MB);  // 16 MB  [38,54)
  unsigned short* qh = (unsigned short*)(ws + 54 * MB);  // 16 MB  [54,70)
  unsigned short* vT = (unsigned short*)(ws + 70 * MB);  // 16 MB  [70,86)
  float* rsum = (float*)(ws + 86 * MB);                  // 32 KB

  // 1) converts (x + 3 W) + rsum zero-init (last 8 blocks)
  cvt_kernel<<<11272, 256, 0, stream>>>(x, Wk, Wq, Wv, xh, rsum);
  // 2) QKV projections; z=2 operand-swapped -> writes vT directly
  qkv_gemm_kernel<<<dim3(24, 64), 256, 0, stream>>>(xh, wh, bk, bq, bv,
                                                    kh, qh, vT);
  // 3) masked exp(scores) + fused row-sum atomics (triangular grid)
  scores_kernel<<<dim3(136, 4), 256, 0, stream>>>(kh, qh, P, rsum);
  // 4) (P @ v) * (1/rsum) -> out
  pv_gemm_kernel<<<dim3(8, 16, 4), 256, 0, stream>>>(P, vT, rsum, out);
}